// Round 3
// baseline (2567.799 us; speedup 1.0000x reference)
//
#include <hip/hip_runtime.h>
#include <hip/hip_bf16.h>

#define B_   64
#define T_   512
#define E_   300
#define U_   512
#define G4_  2048
#define D1_  1024
#define D2_  1024
#define NC_  20
#define KP_  320          // E_ padded to multiple of 32 for MFMA

typedef __bf16 bf16x8 __attribute__((ext_vector_type(8)));
typedef float  f32x4  __attribute__((ext_vector_type(4)));

__device__ __forceinline__ float sigmoidf_(float x) { return 1.0f / (1.0f + __expf(-x)); }

__device__ __forceinline__ void gl_lds16(const void* g, void* l) {
    __builtin_amdgcn_global_load_lds(
        (const __attribute__((address_space(1))) unsigned int*)g,
        (__attribute__((address_space(3))) unsigned int*)l, 16, 0, 0);
}

// coherent single dwordx4 reload (retry path)
__device__ __forceinline__ uint4 cload4(const uint4* p) {
    uint4 t;
    asm volatile("global_load_dwordx4 %0, %1, off sc0 sc1\n\ts_waitcnt vmcnt(0)"
                 : "=v"(t) : "v"(p) : "memory");
    return t;
}

// ---------------------------------------------------------------------------
// init: zero stamped h buffer (2 parities x 64 batches x 256 qwords = 256KB)
// ---------------------------------------------------------------------------
__global__ void init_kernel(uint4* __restrict__ hz) {
    int idx = blockIdx.x * 256 + threadIdx.x;   // grid 64 -> 16384 uint4
    hz[idx] = (uint4){0u, 0u, 0u, 0u};
}

// ---------------------------------------------------------------------------
// prep: Wx (300x2048 f32) -> WxT[2048][320] bf16 (transposed, K zero-padded)
// ---------------------------------------------------------------------------
__global__ __launch_bounds__(256) void prep_wxT(const float* __restrict__ Wx,
                                                __hip_bfloat16* __restrict__ wxT) {
    __shared__ __hip_bfloat16 t[64][65];
    const int n0 = blockIdx.x * 64;   // 32 tiles
    const int k0 = blockIdx.y * 64;   // 5 tiles
    const int tid = threadIdx.x;
    for (int i = tid; i < 4096; i += 256) {
        int r = i >> 6, c = i & 63;                 // r = k-local, c = n-local
        int k = k0 + r;
        float v = (k < E_) ? Wx[(size_t)k * G4_ + n0 + c] : 0.f;
        t[r][c] = __float2bfloat16(v);
    }
    __syncthreads();
    for (int i = tid; i < 4096; i += 256) {
        int r = i >> 6, c = i & 63;                 // r = n-local, c = k-local
        wxT[(size_t)(n0 + r) * KP_ + k0 + c] = t[c][r];
    }
}

// ---------------------------------------------------------------------------
// prep: gather + cvt  xb[bt][k] = bf16(emb[tokens[bt]][k]), zero-padded K
// ---------------------------------------------------------------------------
__global__ __launch_bounds__(256) void prep_xb(const int* __restrict__ tokens,
                                               const float* __restrict__ emb,
                                               __hip_bfloat16* __restrict__ xb) {
    const int row = blockIdx.x * 4 + (threadIdx.x >> 6);
    const int ln  = threadIdx.x & 63;
    const int tok = tokens[row];
    const float* src = emb + (size_t)tok * E_;
    __hip_bfloat16* dst = xb + (size_t)row * KP_;
    for (int k = ln; k < KP_; k += 64)
        dst[k] = (k < E_) ? __float2bfloat16(src[k]) : __float2bfloat16(0.f);
}

// ---------------------------------------------------------------------------
// xg GEMM (MFMA): xg[t][b][n] = xb[bt] @ WxT^T + bias   (m97-style 128x128)
// ---------------------------------------------------------------------------
__global__ __launch_bounds__(256) void xg_gemm(const __hip_bfloat16* __restrict__ xb,
                                               const __hip_bfloat16* __restrict__ wxT,
                                               const float* __restrict__ bias,
                                               __hip_bfloat16* __restrict__ xg) {
    const int n0g = blockIdx.x * 128;   // 16
    const int bt0 = blockIdx.y * 128;   // 256
    const int tid = threadIdx.x;
    const int w   = tid >> 6;
    const int ln  = tid & 63;
    const int fn  = ln & 15;
    const int quad = ln >> 4;
    const int m0  = (w >> 1) * 64;
    const int n0w = (w & 1) * 64;

    __shared__ __align__(16) __hip_bfloat16 As[128 * 32];
    __shared__ __align__(16) __hip_bfloat16 Bs[128 * 32];

    f32x4 acc[4][4];
    #pragma unroll
    for (int im = 0; im < 4; ++im)
        #pragma unroll
        for (int in = 0; in < 4; ++in)
            acc[im][in] = (f32x4){0.f, 0.f, 0.f, 0.f};

    // staging addresses (per k-step add 32 elements)
    const __hip_bfloat16* ga = xb  + (size_t)(bt0 + w * 32 + (ln >> 2)) * KP_ + (ln & 3) * 8;
    const __hip_bfloat16* gb = wxT + (size_t)(n0g + w * 32 + (ln >> 2)) * KP_ + (ln & 3) * 8;

    for (int kt = 0; kt < KP_ / 32; ++kt) {
        gl_lds16(ga,             &As[(w * 32) * 32]);
        gl_lds16(ga + 16 * KP_,  &As[(w * 32 + 16) * 32]);
        gl_lds16(gb,             &Bs[(w * 32) * 32]);
        gl_lds16(gb + 16 * KP_,  &Bs[(w * 32 + 16) * 32]);
        ga += 32; gb += 32;
        __syncthreads();

        bf16x8 af[4], bf[4];
        #pragma unroll
        for (int im = 0; im < 4; ++im)
            af[im] = *(const bf16x8*)&As[(m0 + im * 16 + fn) * 32 + quad * 8];
        #pragma unroll
        for (int in = 0; in < 4; ++in)
            bf[in] = *(const bf16x8*)&Bs[(n0w + in * 16 + fn) * 32 + quad * 8];
        #pragma unroll
        for (int im = 0; im < 4; ++im)
            #pragma unroll
            for (int in = 0; in < 4; ++in)
                acc[im][in] = __builtin_amdgcn_mfma_f32_16x16x32_bf16(
                    af[im], bf[in], acc[im][in], 0, 0, 0);
        __syncthreads();
    }

    // epilogue: D lane holds rows quad*4+r, col fn of each 16x16 tile
    #pragma unroll
    for (int in = 0; in < 4; ++in) {
        const int n = n0g + n0w + in * 16 + fn;
        const float bv = bias[n];
        #pragma unroll
        for (int im = 0; im < 4; ++im) {
            #pragma unroll
            for (int r = 0; r < 4; ++r) {
                int m = bt0 + m0 + im * 16 + quad * 4 + r;   // bt = b*T + t
                int bb = m >> 9, tt = m & 511;
                xg[(size_t)(tt * B_ + bb) * G4_ + n] =
                    __float2bfloat16(acc[im][in][r] + bv);
            }
        }
    }
}

// ---------------------------------------------------------------------------
// LSTM: 256 blocks = 64 unit-slices x 4 batch-groups; weight-stationary.
//
// Round-3 exchange: NO flags, NO fences, NO store drains. Each 8B h qword is
// self-validating: {payload = 2xbf16, seq = step stamp}. Producer stores
// stamped qwords (sc0 sc1) and proceeds. Consumer's load IS the poll:
// batched 8x dwordx4 + per-qword seq check + per-qword retry. Parity
// double-buffer; publishing stamp s implies all blocks consumed stamp s-1,
// so exact-match seq checks are race-free. 8B natural atomicity makes
// ordering irrelevant. Retries are self-throttled (load RT + s_sleep) and
// spread over 32KB (no hot flag lines). Tail barrier is RAW s_barrier (no
// implicit vmcnt drain) - keeps waves together without paying a store-ack
// drain; a consumer load passing its own in-flight store just retries.
// xg reads are prefetched one step ahead so the stamped batch's vmcnt(0)
// doesn't serialize behind HBM-latency xg loads.
// ---------------------------------------------------------------------------
__global__ __launch_bounds__(256) void lstm_kernel(const __hip_bfloat16* __restrict__ xg,
                                                   const int* __restrict__ tokens,
                                                   const float* __restrict__ Wh,
                                                   uint2* __restrict__ hbuf2) {
    const int tid  = threadIdx.x;
    const int lane = tid & 63;
    const int wave = tid >> 6;
    const int x  = blockIdx.x & 7;
    const int r_ = blockIdx.x >> 3;
    const int ub = x * 8 + (r_ & 7);    // unit-slice: units [ub*8, ub*8+8)
    const int g  = r_ >> 3;             // batch-group: batches [g*16, g*16+16)
    const int u0 = ub * 8;

    __shared__ __align__(16) __hip_bfloat16 whsT[32][520];  // [c][k]
    __shared__ __align__(16) __hip_bfloat16 hs[16][520];    // [m][k]
    __shared__ float gbuf[16][32];
    __shared__ unsigned mask_lds[16][16];                   // token!=0 bitmask

    for (int idx = tid; idx < 32 * 512; idx += 256) {
        int c = idx & 31, k = idx >> 5;
        int col = ((c >> 3) << 9) + u0 + (c & 7);
        whsT[c][k] = __float2bfloat16(Wh[(size_t)k * G4_ + col]);
    }
    {
        int m = tid >> 4, wi = tid & 15;
        const int4* tp = (const int4*)(tokens + (size_t)(g * 16 + m) * T_ + wi * 32);
        unsigned bits = 0;
        #pragma unroll
        for (int q = 0; q < 8; ++q) {
            int4 v = tp[q];
            bits |= (v.x != 0 ? 1u : 0u) << (q * 4 + 0);
            bits |= (v.y != 0 ? 1u : 0u) << (q * 4 + 1);
            bits |= (v.z != 0 ? 1u : 0u) << (q * 4 + 2);
            bits |= (v.w != 0 ? 1u : 0u) << (q * 4 + 3);
        }
        mask_lds[m][wi] = bits;
    }

    float c0 = 0.f, c1 = 0.f, h0 = 0.f, h1 = 0.f;

    const int fn   = lane & 15;
    const int quad = lane >> 4;
    const int fc   = wave * 16 + fn;
    const int fcol = ((fc >> 3) << 9) + u0 + (fc & 7);

    __syncthreads();

    // xg prefetch for s=0
    float xvp[4];
    if (wave < 2) {
        #pragma unroll
        for (int r = 0; r < 4; ++r)
            xvp[r] = __bfloat162float(
                xg[(size_t)(0 * B_ + g * 16 + quad * 4 + r) * G4_ + fcol]);
    }

    for (int s = 0; s < T_; ++s) {
        float xv[4];
        if (wave < 2) {
            #pragma unroll
            for (int r = 0; r < 4; ++r) xv[r] = xvp[r];
        }

        // ---- stamped h load: batched issue, per-qword validate+retry ----
        {
            const uint4* hp = (const uint4*)(hbuf2 +
                (size_t)((s & 1) * (B_ * 256) + (g * 16) * 256)) + tid;
            uint4 t0, t1, t2, t3, t4, t5, t6, t7;
            asm volatile(
                "global_load_dwordx4 %0, %8,  off sc0 sc1\n\t"
                "global_load_dwordx4 %1, %9,  off sc0 sc1\n\t"
                "global_load_dwordx4 %2, %10, off sc0 sc1\n\t"
                "global_load_dwordx4 %3, %11, off sc0 sc1\n\t"
                "global_load_dwordx4 %4, %12, off sc0 sc1\n\t"
                "global_load_dwordx4 %5, %13, off sc0 sc1\n\t"
                "global_load_dwordx4 %6, %14, off sc0 sc1\n\t"
                "global_load_dwordx4 %7, %15, off sc0 sc1\n\t"
                "s_waitcnt vmcnt(0)"
                : "=&v"(t0), "=&v"(t1), "=&v"(t2), "=&v"(t3),
                  "=&v"(t4), "=&v"(t5), "=&v"(t6), "=&v"(t7)
                : "v"(hp), "v"(hp + 256), "v"(hp + 512), "v"(hp + 768),
                  "v"(hp + 1024), "v"(hp + 1280), "v"(hp + 1536), "v"(hp + 1792)
                : "memory");

            const unsigned tgt = (unsigned)s;
            #define RETRY_(tt, pp) \
                while (tt.y != tgt || tt.w != tgt) { \
                    __builtin_amdgcn_s_sleep(1); tt = cload4(pp); }
            RETRY_(t0, hp);        RETRY_(t1, hp + 256);
            RETRY_(t2, hp + 512);  RETRY_(t3, hp + 768);
            RETRY_(t4, hp + 1024); RETRY_(t5, hp + 1280);
            RETRY_(t6, hp + 1536); RETRY_(t7, hp + 1792);
            #undef RETRY_

            // unpack into hs: uint4 index u -> batch u>>7, units (u&127)*4..+3
            #define HSW_(tt, k) { int u = tid + 256 * (k); \
                *(uint2*)&hs[u >> 7][(u & 127) * 4] = (uint2){tt.x, tt.z}; }
            HSW_(t0, 0) HSW_(t1, 1) HSW_(t2, 2) HSW_(t3, 3)
            HSW_(t4, 4) HSW_(t5, 5) HSW_(t6, 6) HSW_(t7, 7)
            #undef HSW_
        }
        __syncthreads();

        // xg prefetch for s+1 (completes under MFMA + elementwise)
        if (wave < 2 && s + 1 < T_) {
            #pragma unroll
            for (int r = 0; r < 4; ++r)
                xvp[r] = __bfloat162float(
                    xg[(size_t)((s + 1) * B_ + g * 16 + quad * 4 + r) * G4_ + fcol]);
        }

        if (wave < 2) {
            f32x4 acc;
            #pragma unroll
            for (int r = 0; r < 4; ++r) acc[r] = xv[r];
            const __hip_bfloat16* arow = &hs[fn][quad * 8];
            const __hip_bfloat16* brow = &whsT[fc][quad * 8];
            #pragma unroll
            for (int kk = 0; kk < 16; ++kk) {
                bf16x8 av = *(const bf16x8*)(arow + kk * 32);
                bf16x8 bv = *(const bf16x8*)(brow + kk * 32);
                acc = __builtin_amdgcn_mfma_f32_16x16x32_bf16(av, bv, acc, 0, 0, 0);
            }
            #pragma unroll
            for (int r = 0; r < 4; ++r)
                gbuf[quad * 4 + r][fc] = acc[r];
        }
        __syncthreads();

        if (tid < 64) {
            const int m  = tid >> 2;
            const int u2 = (tid & 3) << 1;
            float gi0 = sigmoidf_(gbuf[m][u2]),      gi1 = sigmoidf_(gbuf[m][u2 + 1]);
            float gf0 = sigmoidf_(gbuf[m][8 + u2]),  gf1 = sigmoidf_(gbuf[m][9 + u2]);
            float gc0 = gbuf[m][16 + u2],            gc1 = gbuf[m][17 + u2];
            float go0 = sigmoidf_(gbuf[m][24 + u2]), go1 = sigmoidf_(gbuf[m][25 + u2]);
            float cn0 = gf0 * c0 + gi0 * fmaxf(gc0, 0.f);
            float cn1 = gf1 * c1 + gi1 * fmaxf(gc1, 0.f);
            float hn0 = go0 * fmaxf(cn0, 0.f);
            float hn1 = go1 * fmaxf(cn1, 0.f);
            if ((mask_lds[m][s >> 5] >> (s & 31)) & 1u) {
                c0 = cn0; c1 = cn1; h0 = hn0; h1 = hn1;
            }
            __hip_bfloat162 hv;
            hv.x = __float2bfloat16(h0);
            hv.y = __float2bfloat16(h1);
            unsigned wv;
            __builtin_memcpy(&wv, &hv, 4);
            // stamped publish: {payload, seq=s+1}; no drain, no flag
            uint2 val; val.x = wv; val.y = (unsigned)(s + 1);
            uint2* dst = hbuf2 + (size_t)(((s + 1) & 1) * (B_ * 256) +
                                          (g * 16 + m) * 256 + ub * 4 + (tid & 3));
            asm volatile("global_store_dwordx2 %0, %1, off sc0 sc1"
                         :: "v"(dst), "v"(val) : "memory");
        }
        // raw barrier: keep waves together (no early spin) WITHOUT the
        // implicit vmcnt(0) store-ack drain of __syncthreads. A consumer
        // load overtaking its own in-flight store merely retries.
        __builtin_amdgcn_s_barrier();
    }
}

// ---------------------------------------------------------------------------
// FC layers (fc1 reads stamped h buffer, parity 0 = stamp T_)
// ---------------------------------------------------------------------------
__global__ __launch_bounds__(256) void fc1_kernel(const uint2* __restrict__ hb2,
                                                  const float* __restrict__ W,
                                                  const float* __restrict__ bias,
                                                  float* __restrict__ y) {
    int b = blockIdx.x >> 2, ch = blockIdx.x & 3;
    __shared__ float xrow[U_];
    for (int i = threadIdx.x; i < U_ / 2; i += 256) {
        uint2 v = hb2[(size_t)b * 256 + i];
        __hip_bfloat162 hv;
        __builtin_memcpy(&hv, &v.x, 4);
        xrow[2 * i]     = __bfloat162float(hv.x);
        xrow[2 * i + 1] = __bfloat162float(hv.y);
    }
    __syncthreads();
    int n = ch * 256 + threadIdx.x;
    float acc = 0.f;
    #pragma unroll 4
    for (int k = 0; k < U_; ++k) acc = fmaf(xrow[k], W[(size_t)k * D1_ + n], acc);
    y[b * D1_ + n] = fmaxf(acc + bias[n], 0.f);
}

__global__ __launch_bounds__(256) void fc2_kernel(const float* __restrict__ x,
                                                  const float* __restrict__ W,
                                                  const float* __restrict__ bias,
                                                  float* __restrict__ y) {
    int b = blockIdx.x >> 2, ch = blockIdx.x & 3;
    __shared__ float xrow[D1_];
    for (int i = threadIdx.x; i < D1_; i += 256) xrow[i] = x[b * D1_ + i];
    __syncthreads();
    int n = ch * 256 + threadIdx.x;
    float acc = 0.f;
    #pragma unroll 4
    for (int k = 0; k < D1_; ++k) acc = fmaf(xrow[k], W[(size_t)k * D2_ + n], acc);
    y[b * D2_ + n] = fmaxf(acc + bias[n], 0.f);
}

// ---------------------------------------------------------------------------
// logits + softmax
// ---------------------------------------------------------------------------
__global__ __launch_bounds__(64) void out_kernel(const float* __restrict__ h2,
                                                 const float* __restrict__ Wo,
                                                 const float* __restrict__ bo,
                                                 float* __restrict__ out) {
    int b = blockIdx.x;
    __shared__ float xrow[D2_];
    __shared__ float lg[NC_];
    __shared__ float red[2];
    for (int i = threadIdx.x; i < D2_; i += 64) xrow[i] = h2[b * D2_ + i];
    __syncthreads();
    if (threadIdx.x < NC_) {
        float a = bo[threadIdx.x];
        for (int k = 0; k < D2_; ++k) a = fmaf(xrow[k], Wo[k * NC_ + threadIdx.x], a);
        lg[threadIdx.x] = a;
    }
    __syncthreads();
    if (threadIdx.x == 0) {
        float mx = lg[0];
        for (int c = 1; c < NC_; ++c) mx = fmaxf(mx, lg[c]);
        float sm = 0.f;
        for (int c = 0; c < NC_; ++c) sm += expf(lg[c] - mx);
        red[0] = mx; red[1] = 1.0f / sm;
    }
    __syncthreads();
    if (threadIdx.x < NC_)
        out[b * NC_ + threadIdx.x] = expf(lg[threadIdx.x] - red[0]) * red[1];
}

// ---------------------------------------------------------------------------
extern "C" void kernel_launch(void* const* d_in, const int* in_sizes, int n_in,
                              void* d_out, int out_size, void* d_ws, size_t ws_size,
                              hipStream_t stream) {
    const int*   tokens = (const int*)d_in[0];
    const float* emb    = (const float*)d_in[1];
    const float* Wx     = (const float*)d_in[2];
    const float* Wh     = (const float*)d_in[3];
    const float* b      = (const float*)d_in[4];
    const float* W1     = (const float*)d_in[5];
    const float* b1     = (const float*)d_in[6];
    const float* W2     = (const float*)d_in[7];
    const float* b2     = (const float*)d_in[8];
    const float* Wo     = (const float*)d_in[9];
    const float* bo     = (const float*)d_in[10];
    float* out = (float*)d_out;

    char* ws = (char*)d_ws;
    const size_t XG_BYTES   = (size_t)T_ * B_ * G4_ * 2;        // 134,217,728
    const size_t HB2_BYTES  = (size_t)2 * B_ * 256 * 8;         // 262,144 stamped h
    __hip_bfloat16* xg  = (__hip_bfloat16*)ws;
    uint2* hbuf2        = (uint2*)(ws + XG_BYTES);
    char* p = ws + XG_BYTES + HB2_BYTES;
    float* h1            = (float*)p;                 p += (size_t)B_ * D1_ * 4;
    float* h2            = (float*)p;                 p += (size_t)B_ * D2_ * 4;
    __hip_bfloat16* xb   = (__hip_bfloat16*)p;        p += (size_t)B_ * T_ * KP_ * 2;
    __hip_bfloat16* wxT  = (__hip_bfloat16*)p;        // 2048*320*2 = 1.3 MB

    init_kernel<<<64, 256, 0, stream>>>((uint4*)hbuf2);
    prep_wxT<<<dim3(32, 5), 256, 0, stream>>>(Wx, wxT);
    prep_xb<<<(B_ * T_) / 4, 256, 0, stream>>>(tokens, emb, xb);
    xg_gemm<<<dim3(16, 256), 256, 0, stream>>>(xb, wxT, b, xg);
    lstm_kernel<<<256, 256, 0, stream>>>(xg, tokens, Wh, hbuf2);
    fc1_kernel<<<256, 256, 0, stream>>>(hbuf2, W1, b1, h1);
    fc2_kernel<<<256, 256, 0, stream>>>(h1, W2, b2, h2);
    out_kernel<<<64, 64, 0, stream>>>(h2, Wo, bo, out);
}

// Round 4
// 1692.597 us; speedup vs baseline: 1.5171x; 1.5171x over previous
//
#include <hip/hip_runtime.h>
#include <hip/hip_bf16.h>

#define B_   64
#define T_   512
#define E_   300
#define U_   512
#define G4_  2048
#define D1_  1024
#define D2_  1024
#define NC_  20
#define KP_  320          // E_ padded to multiple of 32 for MFMA

typedef __bf16 bf16x8 __attribute__((ext_vector_type(8)));
typedef float  f32x4  __attribute__((ext_vector_type(4)));

__device__ __forceinline__ float sigmoidf_(float x) { return 1.0f / (1.0f + __expf(-x)); }

__device__ __forceinline__ void gl_lds16(const void* g, void* l) {
    __builtin_amdgcn_global_load_lds(
        (const __attribute__((address_space(1))) unsigned int*)g,
        (__attribute__((address_space(3))) unsigned int*)l, 16, 0, 0);
}

// ---------------------------------------------------------------------------
// init: zero hbuf[0] (64x512 bf16) and flags (256 ints)
// ---------------------------------------------------------------------------
__global__ void init_kernel(unsigned int* __restrict__ hz, int* __restrict__ flags) {
    int idx = blockIdx.x * 256 + threadIdx.x;
    if (idx < (B_ * U_ / 2)) hz[idx] = 0u;
    if (idx < 256) flags[idx] = 0;
}

// ---------------------------------------------------------------------------
// prep: Wx (300x2048 f32) -> WxT[2048][320] bf16 (transposed, K zero-padded)
// ---------------------------------------------------------------------------
__global__ __launch_bounds__(256) void prep_wxT(const float* __restrict__ Wx,
                                                __hip_bfloat16* __restrict__ wxT) {
    __shared__ __hip_bfloat16 t[64][65];
    const int n0 = blockIdx.x * 64;   // 32 tiles
    const int k0 = blockIdx.y * 64;   // 5 tiles
    const int tid = threadIdx.x;
    for (int i = tid; i < 4096; i += 256) {
        int r = i >> 6, c = i & 63;                 // r = k-local, c = n-local
        int k = k0 + r;
        float v = (k < E_) ? Wx[(size_t)k * G4_ + n0 + c] : 0.f;
        t[r][c] = __float2bfloat16(v);
    }
    __syncthreads();
    for (int i = tid; i < 4096; i += 256) {
        int r = i >> 6, c = i & 63;                 // r = n-local, c = k-local
        wxT[(size_t)(n0 + r) * KP_ + k0 + c] = t[c][r];
    }
}

// ---------------------------------------------------------------------------
// prep: gather + cvt  xb[bt][k] = bf16(emb[tokens[bt]][k]), zero-padded K
// ---------------------------------------------------------------------------
__global__ __launch_bounds__(256) void prep_xb(const int* __restrict__ tokens,
                                               const float* __restrict__ emb,
                                               __hip_bfloat16* __restrict__ xb) {
    const int row = blockIdx.x * 4 + (threadIdx.x >> 6);
    const int ln  = threadIdx.x & 63;
    const int tok = tokens[row];
    const float* src = emb + (size_t)tok * E_;
    __hip_bfloat16* dst = xb + (size_t)row * KP_;
    for (int k = ln; k < KP_; k += 64)
        dst[k] = (k < E_) ? __float2bfloat16(src[k]) : __float2bfloat16(0.f);
}

// ---------------------------------------------------------------------------
// xg GEMM (MFMA): xg[t][b][n] = xb[bt] @ WxT^T + bias   (m97-style 128x128)
// ---------------------------------------------------------------------------
__global__ __launch_bounds__(256) void xg_gemm(const __hip_bfloat16* __restrict__ xb,
                                               const __hip_bfloat16* __restrict__ wxT,
                                               const float* __restrict__ bias,
                                               __hip_bfloat16* __restrict__ xg) {
    const int n0g = blockIdx.x * 128;   // 16
    const int bt0 = blockIdx.y * 128;   // 256
    const int tid = threadIdx.x;
    const int w   = tid >> 6;
    const int ln  = tid & 63;
    const int fn  = ln & 15;
    const int quad = ln >> 4;
    const int m0  = (w >> 1) * 64;
    const int n0w = (w & 1) * 64;

    __shared__ __align__(16) __hip_bfloat16 As[128 * 32];
    __shared__ __align__(16) __hip_bfloat16 Bs[128 * 32];

    f32x4 acc[4][4];
    #pragma unroll
    for (int im = 0; im < 4; ++im)
        #pragma unroll
        for (int in = 0; in < 4; ++in)
            acc[im][in] = (f32x4){0.f, 0.f, 0.f, 0.f};

    // staging addresses (per k-step add 32 elements)
    const __hip_bfloat16* ga = xb  + (size_t)(bt0 + w * 32 + (ln >> 2)) * KP_ + (ln & 3) * 8;
    const __hip_bfloat16* gb = wxT + (size_t)(n0g + w * 32 + (ln >> 2)) * KP_ + (ln & 3) * 8;

    for (int kt = 0; kt < KP_ / 32; ++kt) {
        gl_lds16(ga,             &As[(w * 32) * 32]);
        gl_lds16(ga + 16 * KP_,  &As[(w * 32 + 16) * 32]);
        gl_lds16(gb,             &Bs[(w * 32) * 32]);
        gl_lds16(gb + 16 * KP_,  &Bs[(w * 32 + 16) * 32]);
        ga += 32; gb += 32;
        __syncthreads();

        bf16x8 af[4], bf[4];
        #pragma unroll
        for (int im = 0; im < 4; ++im)
            af[im] = *(const bf16x8*)&As[(m0 + im * 16 + fn) * 32 + quad * 8];
        #pragma unroll
        for (int in = 0; in < 4; ++in)
            bf[in] = *(const bf16x8*)&Bs[(n0w + in * 16 + fn) * 32 + quad * 8];
        #pragma unroll
        for (int im = 0; im < 4; ++im)
            #pragma unroll
            for (int in = 0; in < 4; ++in)
                acc[im][in] = __builtin_amdgcn_mfma_f32_16x16x32_bf16(
                    af[im], bf[in], acc[im][in], 0, 0, 0);
        __syncthreads();
    }

    // epilogue: D lane holds rows quad*4+r, col fn of each 16x16 tile
    #pragma unroll
    for (int in = 0; in < 4; ++in) {
        const int n = n0g + n0w + in * 16 + fn;
        const float bv = bias[n];
        #pragma unroll
        for (int im = 0; im < 4; ++im) {
            #pragma unroll
            for (int r = 0; r < 4; ++r) {
                int m = bt0 + m0 + im * 16 + quad * 4 + r;   // bt = b*T + t
                int bb = m >> 9, tt = m & 511;
                xg[(size_t)(tt * B_ + bb) * G4_ + n] =
                    __float2bfloat16(acc[im][in][r] + bv);
            }
        }
    }
}

// ---------------------------------------------------------------------------
// LSTM: 128 blocks = 32 unit-slices x 4 batch-groups; weight-stationary.
//
// Round-4 change: GEOMETRY ONLY (protocol is verbatim the verified-best R0).
// Model fitted over R0-R3: lstm time scales with coherent h-broadcast VOLUME
// (N_blocks_per_group x 16KB per step), i.e. coherence-point service-rate
// bound (~1.7-2.0 TB/s), not RT-latency bound. So: 16 units/block instead
// of 8 -> 32 blocks/group -> exchange volume halves (2.1 GB -> 1.05 GB).
// All 4 waves now do MFMA (16x16 tile each); elementwise uses 128 threads.
// LDS: whsT 65KB + hs 16.6KB + gbuf 4KB + mask 1KB = 88KB.
// ---------------------------------------------------------------------------
__global__ __launch_bounds__(256) void lstm_kernel(const __hip_bfloat16* __restrict__ xg,
                                                   const int* __restrict__ tokens,
                                                   const float* __restrict__ Wh,
                                                   __hip_bfloat16* __restrict__ hbuf,
                                                   int* __restrict__ flags) {
    const int tid  = threadIdx.x;
    const int lane = tid & 63;
    const int wave = tid >> 6;
    const int x  = blockIdx.x & 7;      // spread across XCDs
    const int r_ = blockIdx.x >> 3;     // 0..15
    const int ub = x * 4 + (r_ & 3);    // unit-slice 0..31: units [ub*16, ub*16+16)
    const int g  = r_ >> 2;             // batch-group 0..3: batches [g*16, g*16+16)
    const int u0 = ub * 16;

    __shared__ __align__(16) __hip_bfloat16 whsT[64][520];  // [c][k] 64 gate-cols
    __shared__ __align__(16) __hip_bfloat16 hs[16][520];    // [m][k]
    __shared__ float gbuf[16][64];
    __shared__ unsigned mask_lds[16][16];                   // token!=0 bitmask

    // stage Wh slice: gate-col c (c>>4 = gate, c&15 = unit-local), k = 0..511
    for (int idx = tid; idx < 64 * 512; idx += 256) {
        int c = idx & 63, k = idx >> 6;
        int col = ((c >> 4) << 9) + u0 + (c & 15);
        whsT[c][k] = __float2bfloat16(Wh[(size_t)k * G4_ + col]);
    }
    {
        int m = tid >> 4, wi = tid & 15;
        const int4* tp = (const int4*)(tokens + (size_t)(g * 16 + m) * T_ + wi * 32);
        unsigned bits = 0;
        #pragma unroll
        for (int q = 0; q < 8; ++q) {
            int4 v = tp[q];
            bits |= (v.x != 0 ? 1u : 0u) << (q * 4 + 0);
            bits |= (v.y != 0 ? 1u : 0u) << (q * 4 + 1);
            bits |= (v.z != 0 ? 1u : 0u) << (q * 4 + 2);
            bits |= (v.w != 0 ? 1u : 0u) << (q * 4 + 3);
        }
        mask_lds[m][wi] = bits;
    }

    float c0 = 0.f, c1 = 0.f, h0 = 0.f, h1 = 0.f;
    int* gflags = flags + g * 64;

    const int fn   = lane & 15;
    const int quad = lane >> 4;
    const int fc   = wave * 16 + fn;                  // 0..63 gate-col
    const int fcol = ((fc >> 4) << 9) + u0 + (fc & 15);

    __syncthreads();

    for (int s = 0; s < T_; ++s) {
        float xv[4];
        {
            #pragma unroll
            for (int r = 0; r < 4; ++r)
                xv[r] = __bfloat162float(
                    xg[(size_t)(s * B_ + g * 16 + quad * 4 + r) * G4_ + fcol]);
        }

        if (s > 0) {
            if (tid < 32) {
                while (__hip_atomic_load(&gflags[tid], __ATOMIC_RELAXED,
                                         __HIP_MEMORY_SCOPE_AGENT) < s)
                    __builtin_amdgcn_s_sleep(2);
            }
            __syncthreads();
        }

        {
            const uint4* hp = (const uint4*)(hbuf + (size_t)((s & 1) * B_ + g * 16) * U_);
            uint4 t0, t1, t2, t3;
            asm volatile(
                "global_load_dwordx4 %0, %4, off sc0 sc1\n\t"
                "global_load_dwordx4 %1, %5, off sc0 sc1\n\t"
                "global_load_dwordx4 %2, %6, off sc0 sc1\n\t"
                "s_waitcnt vmcnt(0)\n\t"
                "global_load_dwordx4 %3, %7, off sc0 sc1\n\t"
                "s_waitcnt vmcnt(0)"
                : "=&v"(t0), "=&v"(t1), "=&v"(t2), "=&v"(t3)
                : "v"(hp + tid), "v"(hp + tid + 256), "v"(hp + tid + 512),
                  "v"(hp + tid + 768)
                : "memory");
            int i0 = tid;        *((uint4*)&hs[i0 >> 6][(i0 & 63) * 8]) = t0;
            int i1 = tid + 256;  *((uint4*)&hs[i1 >> 6][(i1 & 63) * 8]) = t1;
            int i2 = tid + 512;  *((uint4*)&hs[i2 >> 6][(i2 & 63) * 8]) = t2;
            int i3 = tid + 768;  *((uint4*)&hs[i3 >> 6][(i3 & 63) * 8]) = t3;
        }
        __syncthreads();

        {
            // all 4 waves: 16x16 output tile (16 batches x 16 gate-cols) K=512
            f32x4 acc;
            #pragma unroll
            for (int r = 0; r < 4; ++r) acc[r] = xv[r];
            const __hip_bfloat16* arow = &hs[fn][quad * 8];
            const __hip_bfloat16* brow = &whsT[fc][quad * 8];
            #pragma unroll
            for (int kk = 0; kk < 16; ++kk) {
                bf16x8 av = *(const bf16x8*)(arow + kk * 32);
                bf16x8 bv = *(const bf16x8*)(brow + kk * 32);
                acc = __builtin_amdgcn_mfma_f32_16x16x32_bf16(av, bv, acc, 0, 0, 0);
            }
            #pragma unroll
            for (int r = 0; r < 4; ++r)
                gbuf[quad * 4 + r][fc] = acc[r];
        }
        __syncthreads();

        if (tid < 128) {
            const int m  = tid >> 3;            // batch-local 0..15
            const int u2 = (tid & 7) << 1;      // unit-local 0,2,..,14
            float gi0 = sigmoidf_(gbuf[m][u2]),       gi1 = sigmoidf_(gbuf[m][u2 + 1]);
            float gf0 = sigmoidf_(gbuf[m][16 + u2]),  gf1 = sigmoidf_(gbuf[m][17 + u2]);
            float gc0 = gbuf[m][32 + u2],             gc1 = gbuf[m][33 + u2];
            float go0 = sigmoidf_(gbuf[m][48 + u2]),  go1 = sigmoidf_(gbuf[m][49 + u2]);
            float cn0 = gf0 * c0 + gi0 * fmaxf(gc0, 0.f);
            float cn1 = gf1 * c1 + gi1 * fmaxf(gc1, 0.f);
            float hn0 = go0 * fmaxf(cn0, 0.f);
            float hn1 = go1 * fmaxf(cn1, 0.f);
            if ((mask_lds[m][s >> 5] >> (s & 31)) & 1u) {
                c0 = cn0; c1 = cn1; h0 = hn0; h1 = hn1;
            }
            __hip_bfloat162 hv;
            hv.x = __float2bfloat16(h0);
            hv.y = __float2bfloat16(h1);
            unsigned wv;
            __builtin_memcpy(&wv, &hv, 4);
            unsigned* dst = (unsigned*)hbuf +
                (((((s + 1) & 1) * B_ + g * 16 + m) * U_ + u0 + u2) >> 1);
            __hip_atomic_store(dst, wv, __ATOMIC_RELAXED, __HIP_MEMORY_SCOPE_AGENT);
        }
        __syncthreads();   // implicit vmcnt(0): all h store-acks drained (release)
        if (tid == 0)
            __hip_atomic_store(&gflags[ub], s + 1, __ATOMIC_RELAXED,
                               __HIP_MEMORY_SCOPE_AGENT);
    }
}

// ---------------------------------------------------------------------------
// FC layers
// ---------------------------------------------------------------------------
__global__ __launch_bounds__(256) void fc1_kernel(const __hip_bfloat16* __restrict__ h,
                                                  const float* __restrict__ W,
                                                  const float* __restrict__ bias,
                                                  float* __restrict__ y) {
    int b = blockIdx.x >> 2, ch = blockIdx.x & 3;
    __shared__ float xrow[U_];
    for (int i = threadIdx.x; i < U_; i += 256)
        xrow[i] = __bfloat162float(h[b * U_ + i]);
    __syncthreads();
    int n = ch * 256 + threadIdx.x;
    float acc = 0.f;
    #pragma unroll 4
    for (int k = 0; k < U_; ++k) acc = fmaf(xrow[k], W[(size_t)k * D1_ + n], acc);
    y[b * D1_ + n] = fmaxf(acc + bias[n], 0.f);
}

__global__ __launch_bounds__(256) void fc2_kernel(const float* __restrict__ x,
                                                  const float* __restrict__ W,
                                                  const float* __restrict__ bias,
                                                  float* __restrict__ y) {
    int b = blockIdx.x >> 2, ch = blockIdx.x & 3;
    __shared__ float xrow[D1_];
    for (int i = threadIdx.x; i < D1_; i += 256) xrow[i] = x[b * D1_ + i];
    __syncthreads();
    int n = ch * 256 + threadIdx.x;
    float acc = 0.f;
    #pragma unroll 4
    for (int k = 0; k < D1_; ++k) acc = fmaf(xrow[k], W[(size_t)k * D2_ + n], acc);
    y[b * D2_ + n] = fmaxf(acc + bias[n], 0.f);
}

// ---------------------------------------------------------------------------
// logits + softmax
// ---------------------------------------------------------------------------
__global__ __launch_bounds__(64) void out_kernel(const float* __restrict__ h2,
                                                 const float* __restrict__ Wo,
                                                 const float* __restrict__ bo,
                                                 float* __restrict__ out) {
    int b = blockIdx.x;
    __shared__ float xrow[D2_];
    __shared__ float lg[NC_];
    __shared__ float red[2];
    for (int i = threadIdx.x; i < D2_; i += 64) xrow[i] = h2[b * D2_ + i];
    __syncthreads();
    if (threadIdx.x < NC_) {
        float a = bo[threadIdx.x];
        for (int k = 0; k < D2_; ++k) a = fmaf(xrow[k], Wo[k * NC_ + threadIdx.x], a);
        lg[threadIdx.x] = a;
    }
    __syncthreads();
    if (threadIdx.x == 0) {
        float mx = lg[0];
        for (int c = 1; c < NC_; ++c) mx = fmaxf(mx, lg[c]);
        float sm = 0.f;
        for (int c = 0; c < NC_; ++c) sm += expf(lg[c] - mx);
        red[0] = mx; red[1] = 1.0f / sm;
    }
    __syncthreads();
    if (threadIdx.x < NC_)
        out[b * NC_ + threadIdx.x] = expf(lg[threadIdx.x] - red[0]) * red[1];
}

// ---------------------------------------------------------------------------
extern "C" void kernel_launch(void* const* d_in, const int* in_sizes, int n_in,
                              void* d_out, int out_size, void* d_ws, size_t ws_size,
                              hipStream_t stream) {
    const int*   tokens = (const int*)d_in[0];
    const float* emb    = (const float*)d_in[1];
    const float* Wx     = (const float*)d_in[2];
    const float* Wh     = (const float*)d_in[3];
    const float* b      = (const float*)d_in[4];
    const float* W1     = (const float*)d_in[5];
    const float* b1     = (const float*)d_in[6];
    const float* W2     = (const float*)d_in[7];
    const float* b2     = (const float*)d_in[8];
    const float* Wo     = (const float*)d_in[9];
    const float* bo     = (const float*)d_in[10];
    float* out = (float*)d_out;

    char* ws = (char*)d_ws;
    const size_t XG_BYTES   = (size_t)T_ * B_ * G4_ * 2;        // 134,217,728
    const size_t HBUF_BYTES = (size_t)2 * B_ * U_ * 2;          // 131,072
    __hip_bfloat16* xg   = (__hip_bfloat16*)ws;
    __hip_bfloat16* hbuf = (__hip_bfloat16*)(ws + XG_BYTES);
    int* flags           = (int*)(ws + XG_BYTES + HBUF_BYTES);
    char* p = ws + XG_BYTES + HBUF_BYTES + 1024;
    float* h1            = (float*)p;                 p += (size_t)B_ * D1_ * 4;
    float* h2            = (float*)p;                 p += (size_t)B_ * D2_ * 4;
    __hip_bfloat16* xb   = (__hip_bfloat16*)p;        p += (size_t)B_ * T_ * KP_ * 2;
    __hip_bfloat16* wxT  = (__hip_bfloat16*)p;        // 2048*320*2 = 1.3 MB

    init_kernel<<<64, 256, 0, stream>>>((unsigned int*)hbuf, flags);
    prep_wxT<<<dim3(32, 5), 256, 0, stream>>>(Wx, wxT);
    prep_xb<<<(B_ * T_) / 4, 256, 0, stream>>>(tokens, emb, xb);
    xg_gemm<<<dim3(16, 256), 256, 0, stream>>>(xb, wxT, b, xg);
    lstm_kernel<<<128, 256, 0, stream>>>(xg, tokens, Wh, hbuf, flags);
    fc1_kernel<<<256, 256, 0, stream>>>(hbuf, W1, b1, h1);
    fc2_kernel<<<256, 256, 0, stream>>>(h1, W2, b2, h2);
    out_kernel<<<64, 64, 0, stream>>>(h2, Wo, bo, out);
}